// Round 3
// baseline (695.704 us; speedup 1.0000x reference)
//
#include <hip/hip_runtime.h>

// T=512, B=512, K=8, V=5, H=30, NL=4, NLAB=3
#define TT 512
#define BB 512
#define KK 8
#define HH 30
#define GG 120   // 4*H
#define NLAYER 4
#define SPB 2    // samples per block (ILP over independent recurrences)

__device__ __forceinline__ float rcp_f(float x) { return __builtin_amdgcn_rcpf(x); }
__device__ __forceinline__ float rdlane_f(float v, int l) {
    return __int_as_float(__builtin_amdgcn_readlane(__float_as_int(v), l));
}
// packed f32 FMA, all-VGPR operands (broadcast operand comes from uniform LDS read)
__device__ __forceinline__ float2 pk_fma_v(float2 a, float2 b, float2 c) {
    float2 d;
    asm("v_pk_fma_f32 %0, %1, %2, %3" : "=v"(d) : "v"(a), "v"(b), "v"(c));
    return d;
}
// packed f32 FMA, broadcast operand in SGPR pair (attention epilogue only)
__device__ __forceinline__ float2 pk_fma_s(float2 a, float2 bs, float2 c) {
    float2 d;
    asm("v_pk_fma_f32 %0, %1, %2, %3" : "=v"(d) : "v"(a), "s"(bs), "v"(c));
    return d;
}
__device__ __forceinline__ float2 pk_add(float2 a, float2 b) {
    float2 d;
    asm("v_pk_add_f32 %0, %1, %2" : "=v"(d) : "v"(a), "v"(b));
    return d;
}
// value from lane^32 partner (valid for lanes < 32; lanes >= 32 get own/lo value)
__device__ __forceinline__ float swap32_hi(float x) {
    float a = x, b = x;
    asm("v_permlane32_swap_b32 %0, %1" : "+v"(a), "+v"(b));
    return b;   // lanes<32: x[lane+32]
}

// One block = TWO samples; 4 waves = 4 LSTM layers, SYSTOLIC with barriers.
// R5 (elastic spin + SPB=2) failed correctness with race-shaped errors; the
// spin protocol was the only unprovable component. R6: epoch n, wave w runs
// group g=n-w (4 steps); ONE __syncthreads per epoch orders every cross-wave
// edge. Ring half g&1 is written at epoch g+w, read at g+w+1, overwritten at
// g+w+2 -> provably safe. Per-sample fp math is bit-identical to the R4
// kernel (absmax 0.0). SPB=2 keeps the ILP: each wave interleaves two
// independent recurrences, hiding the LDS-roundtrip + FMA + exp dep chains.
__global__ __launch_bounds__(256) __attribute__((amdgpu_waves_per_eu(1, 1)))
void rnn_fused(
    const int*   __restrict__ xin,  const float* __restrict__ wxin,
    const float* __restrict__ embed,
    const float* __restrict__ Wih,  const float* __restrict__ Whh,
    const float* __restrict__ bih,  const float* __restrict__ bhh,
    const float* __restrict__ W1,   const float* __restrict__ b1,
    const float* __restrict__ W2,   const float* __restrict__ b2,
    const float* __restrict__ fcW,  const float* __restrict__ fcb,
    float* __restrict__ out)
{
    __shared__ alignas(16) float hstore[SPB][TT * HH];   // layer-3 h traces
    __shared__ alignas(16) float seqring[SPB][2][16][32];// pooled-embed (wave-0 private)
    __shared__ alignas(16) int   ringx[SPB][4][16][KK];  // x stream (wave-0 private)
    __shared__ alignas(16) float ringw[SPB][4][16][KK];
    __shared__ alignas(16) float hring[SPB][NLAYER][8][32]; // per-layer h rings
    __shared__ alignas(16) float re_s[5 * HH];           // relu(embed)
    __shared__ alignas(16) float energy_s[TT];           // reused per sample
    __shared__ float red_s[16];
    __shared__ float part_s[8][HH];
    __shared__ float pooled_s[HH];
    __shared__ float logits_s[3];

    const int tid  = threadIdx.x;
    const int wv   = tid >> 6;
    const int lane = tid & 63;
    const int b0   = blockIdx.x * SPB;

    // ---- preamble ----
    if (tid < 5 * HH) re_s[tid] = fmaxf(embed[tid], 0.0f);
    {   // zero hrings: SPB*4*8*32 = 2048 floats = 512 float4
        float4 z; z.x = 0.f; z.y = 0.f; z.z = 0.f; z.w = 0.f;
        ((float4*)hring)[tid]       = z;
        ((float4*)hring)[tid + 256] = z;
    }

    int4 hx[SPB]; float4 hw[SPB];                        // held x/w (wave0, lanes<32)
    #pragma unroll
    for (int s = 0; s < SPB; ++s) { hx[s] = {0,0,0,0}; hw[s] = {0,0,0,0}; }
    if (wv == 0 && lane < 32) {
        const int r = lane >> 1, hf = lane & 1;
        #pragma unroll
        for (int s = 0; s < SPB; ++s) {
            #pragma unroll
            for (int cc = 0; cc < 2; ++cc) {             // chunks 0,1 -> LDS
                long off = ((long)(16 * cc + r) * BB + (b0 + s)) * KK + hf * 4;
                *(int4*)(&ringx[s][cc][r][hf * 4])   = *(const int4*)(xin  + off);
                *(float4*)(&ringw[s][cc][r][hf * 4]) = *(const float4*)(wxin + off);
            }
            long off2 = ((long)(32 + r) * BB + (b0 + s)) * KK + hf * 4; // chunk 2 -> regs
            hx[s] = *(const int4*)(xin  + off2);
            hw[s] = *(const float4*)(wxin + off2);
        }
    }

    // ---- per-lane LSTM weights, XOR-32 gate layout (shared by both samples) ----
    // half0 (lanes 0..31):  rowA = i-row q,    rowB = g-row q+60
    // half1 (lanes 32..63): rowA = f-row q+30, rowB = o-row q+90
    const int half = lane >> 5;
    const int q31  = lane & 31;
    const int qq   = (q31 < HH) ? q31 : (HH - 1);        // clamp dead lanes
    const int rA   = qq + half * HH;                     // 0..59
    const int rB   = rA + 60;                            // 60..119
    float2 wihA[15], wihB[15], whhA[15], whhB[15];
    {
        const float* WihL = Wih + wv * GG * HH;
        const float* WhhL = Whh + wv * GG * HH;
        #pragma unroll
        for (int kk = 0; kk < 15; ++kk) {
            wihA[kk] = *(const float2*)(WihL + rA * HH + 2 * kk);
            wihB[kk] = *(const float2*)(WihL + rB * HH + 2 * kk);
            whhA[kk] = *(const float2*)(WhhL + rA * HH + 2 * kk);
            whhB[kk] = *(const float2*)(WhhL + rB * HH + 2 * kk);
        }
    }
    const float biasA = bih[wv * GG + rA] + bhh[wv * GG + rA];
    const float biasB = bih[wv * GG + rB] + bhh[wv * GG + rB];
    const float mBneg = (lane < 32) ? -2.0f : -1.0f;     // half0: tanh via 2*sig(2x)-1
    const float aB    = (lane < 32) ?  2.0f :  1.0f;
    const float dB    = (lane < 32) ? -1.0f :  0.0f;

    __syncthreads();   // preamble visible (ringx/re_s/hring-zero)

    float c_val[SPB];
    #pragma unroll
    for (int s = 0; s < SPB; ++s) c_val[s] = 0.0f;

    auto do_step = [&](int t) {
        const float* xsrc[SPB];
        const float* hsrc[SPB];
        #pragma unroll
        for (int s = 0; s < SPB; ++s) {
            xsrc[s] = (wv == 0) ? &seqring[s][(t >> 4) & 1][t & 15][0]
                                : &hring[s][wv - 1][t & 7][0];
            hsrc[s] = &hring[s][wv][(t + 7) & 7][0];     // own h from step t-1
        }
        float2 ax0[SPB], ax1[SPB], ah0[SPB], ah1[SPB];
        #pragma unroll
        for (int s = 0; s < SPB; ++s) {
            ax0[s] = {0.f,0.f}; ax1[s] = {0.f,0.f};
            ah0[s] = {0.f,0.f}; ah1[s] = {0.f,0.f};
        }
        #pragma unroll
        for (int k = 0; k < 15; ++k) {
            #pragma unroll
            for (int s = 0; s < SPB; ++s) {
                const float2 xp = *(const float2*)(xsrc[s] + 2 * k);
                const float2 hp = *(const float2*)(hsrc[s] + 2 * k);
                ax0[s] = pk_fma_v(wihA[k], xp, ax0[s]);
                ax1[s] = pk_fma_v(wihB[k], xp, ax1[s]);
                ah0[s] = pk_fma_v(whhA[k], hp, ah0[s]);
                ah1[s] = pk_fma_v(whhB[k], hp, ah1[s]);
            }
        }
        #pragma unroll
        for (int s = 0; s < SPB; ++s) {
            const float2 s0 = pk_add(ax0[s], ah0[s]);
            const float2 s1 = pk_add(ax1[s], ah1[s]);
            const float gA = s0.x + s0.y + biasA;        // i | f
            const float gB = s1.x + s1.y + biasB;        // g | o
            const float actA = rcp_f(1.0f + __expf(-gA));
            const float sB   = rcp_f(1.0f + __expf(gB * mBneg));
            const float actB = fmaf(aB, sB, dB);         // tanh | sigmoid
            const float fI = swap32_hi(actA);            // f from lane+32
            const float oI = swap32_hi(actB);            // o from lane+32
            c_val[s] = fmaf(fI, c_val[s], actA * actB);  // valid on lanes 0..29
            const float tC = fmaf(2.0f, rcp_f(1.0f + __expf(-2.0f * c_val[s])), -1.0f);
            const float hv = oI * tC;
            if (lane < HH) {
                hring[s][wv][t & 7][lane] = hv;          // self (t+1) + next layer
                if (wv == NLAYER - 1) hstore[s][t * HH + lane] = hv;
            }
        }
    };

    // ---- systolic recurrence: epoch n, wave w runs group g=n-w (4 steps) ----
    const int NGROUP = TT / 4;                           // 128
    const int NEPOCH = NGROUP + NLAYER - 1;              // 131
    for (int n = 0; n < NEPOCH; ++n) {
        const int g = n - wv;
        if (g >= 0 && g < NGROUP) {
            const int T0 = 4 * g;
            if (wv == 0 && (T0 & 15) == 0) {             // chunk boundary (private)
                const int c = T0 >> 4;
                if (lane < 32) {
                    const int r = lane >> 1, hf = lane & 1;
                    #pragma unroll
                    for (int s = 0; s < SPB; ++s) {
                        if (c <= 29) {                   // commit chunk c+2
                            const int sl = (c + 2) & 3;
                            *(int4*)(&ringx[s][sl][r][hf * 4])   = hx[s];
                            *(float4*)(&ringw[s][sl][r][hf * 4]) = hw[s];
                        }
                        if (c <= 28) {                   // load chunk c+3
                            long off = ((long)(16 * (c + 3) + r) * BB + (b0 + s)) * KK + hf * 4;
                            hx[s] = *(const int4*)(xin  + off);
                            hw[s] = *(const float4*)(wxin + off);
                        }
                    }
                }
                const int sl = c & 3, par = c & 1;       // gather pooled chunk c
                #pragma unroll
                for (int s = 0; s < SPB; ++s) {
                    #pragma unroll
                    for (int rr = 0; rr < 8; ++rr) {
                        const int o = lane + rr * 64;
                        if (o < 480) {
                            const int tr = o / HH, j = o - tr * HH;
                            int4   xa = *(const int4*)(&ringx[s][sl][tr][0]);
                            int4   xb = *(const int4*)(&ringx[s][sl][tr][4]);
                            float4 wa = *(const float4*)(&ringw[s][sl][tr][0]);
                            float4 wb = *(const float4*)(&ringw[s][sl][tr][4]);
                            float acc = re_s[xa.x * HH + j] * wa.x;
                            acc = fmaf(re_s[xa.y * HH + j], wa.y, acc);
                            acc = fmaf(re_s[xa.z * HH + j], wa.z, acc);
                            acc = fmaf(re_s[xa.w * HH + j], wa.w, acc);
                            acc = fmaf(re_s[xb.x * HH + j], wb.x, acc);
                            acc = fmaf(re_s[xb.y * HH + j], wb.y, acc);
                            acc = fmaf(re_s[xb.z * HH + j], wb.z, acc);
                            acc = fmaf(re_s[xb.w * HH + j], wb.w, acc);
                            seqring[s][par][tr][j] = acc * 0.125f;
                        }
                    }
                }
            }
            do_step(T0 + 0);
            do_step(T0 + 1);
            do_step(T0 + 2);
            do_step(T0 + 3);
        }
        __syncthreads();                                 // orders ALL cross-wave edges
    }

    // (final epoch barrier above also covers hstore completion)

    // ---- attention weights (registers, reused for both samples) ----
    float w1cx[15], w1cy[15];                            // W1 column `lane`
    #pragma unroll
    for (int k = 0; k < 15; ++k) {
        w1cx[k] = W1[(2 * k) * 64 + lane];
        w1cy[k] = W1[(2 * k + 1) * 64 + lane];
    }
    const float b1v = b1[lane];
    const float w2v = W2[lane];
    const float b2v = b2[0];

    for (int s = 0; s < SPB; ++s) {
        // ---- attention, t-per-lane: e_t = relu(h_t @ W1 + b1) @ W2 + b2 ----
        #pragma unroll
        for (int pass = 0; pass < 2; ++pass) {
            const int t = wv * 128 + pass * 64 + lane;   // each lane owns one t
            float2 h2[15];
            #pragma unroll
            for (int k = 0; k < 15; ++k)
                h2[k] = *(const float2*)(&hstore[s][t * HH + 2 * k]);
            float e = b2v;
            for (int u = 0; u < 64; ++u) {               // W1 broadcast via readlane
                float2 acc = {0.f, 0.f};
                #pragma unroll
                for (int k = 0; k < 15; ++k) {
                    float2 wp;
                    wp.x = rdlane_f(w1cx[k], u);
                    wp.y = rdlane_f(w1cy[k], u);
                    acc = pk_fma_s(h2[k], wp, acc);
                }
                const float su = acc.x + acc.y + rdlane_f(b1v, u);
                e = fmaf(fmaxf(su, 0.0f), rdlane_f(w2v, u), e);
            }
            energy_s[t] = e;
        }
        __syncthreads();

        // ---- softmax over T ----
        float mx = -3.0e38f;
        for (int i = tid; i < TT; i += 256) mx = fmaxf(mx, energy_s[i]);
        #pragma unroll
        for (int m = 1; m < 64; m <<= 1) mx = fmaxf(mx, __shfl_xor(mx, m, 64));
        if (lane == 0) red_s[wv] = mx;
        __syncthreads();
        mx = fmaxf(fmaxf(red_s[0], red_s[1]), fmaxf(red_s[2], red_s[3]));
        float ssum = 0.0f;
        for (int i = tid; i < TT; i += 256) {
            float ev = __expf(energy_s[i] - mx);
            energy_s[i] = ev;
            ssum += ev;
        }
        #pragma unroll
        for (int m = 1; m < 64; m <<= 1) ssum += __shfl_xor(ssum, m, 64);
        if (lane == 0) red_s[8 + wv] = ssum;
        __syncthreads();
        const float invS = rcp_f(red_s[8] + red_s[9] + red_s[10] + red_s[11]);

        // ---- pooled_j = sum_t softmax_t * h[t][j] ----
        {
            const int g = tid >> 5, jj = tid & 31;
            if (jj < HH) {
                float part = 0.0f;
                for (int t = g; t < TT; t += 8)
                    part = fmaf(energy_s[t] * invS, hstore[s][t * HH + jj], part);
                part_s[g][jj] = part;
            }
        }
        __syncthreads();
        if (tid < HH) {
            float pv = 0.0f;
            #pragma unroll
            for (int q = 0; q < 8; ++q) pv += part_s[q][tid];
            pooled_s[tid] = pv;
        }
        __syncthreads();

        // ---- FC (30->3) + softmax ----
        if (tid < 3) {
            float acc = fcb[tid];
            #pragma unroll
            for (int k = 0; k < HH; ++k) acc = fmaf(pooled_s[k], fcW[k * 3 + tid], acc);
            logits_s[tid] = acc;
        }
        __syncthreads();
        if (tid == 0) {
            float l0 = logits_s[0], l1 = logits_s[1], l2 = logits_s[2];
            float m3 = fmaxf(l0, fmaxf(l1, l2));
            float e0 = __expf(l0 - m3), e1 = __expf(l1 - m3), e2 = __expf(l2 - m3);
            float inv = rcp_f(e0 + e1 + e2);
            const int bo = (b0 + s) * 3;
            out[bo + 0] = e0 * inv; out[bo + 1] = e1 * inv; out[bo + 2] = e2 * inv;
        }
        __syncthreads();   // protect energy_s/red_s/part_s/pooled_s/logits_s reuse
    }
}

extern "C" void kernel_launch(void* const* d_in, const int* in_sizes, int n_in,
                              void* d_out, int out_size, void* d_ws, size_t ws_size,
                              hipStream_t stream)
{
    (void)in_sizes; (void)n_in; (void)d_ws; (void)ws_size; (void)out_size;
    rnn_fused<<<BB / SPB, 256, 0, stream>>>(
        (const int*)  d_in[0],  (const float*)d_in[1],  (const float*)d_in[2],
        (const float*)d_in[3],  (const float*)d_in[4],  (const float*)d_in[5],
        (const float*)d_in[6],  (const float*)d_in[7],  (const float*)d_in[8],
        (const float*)d_in[9],  (const float*)d_in[10], (const float*)d_in[11],
        (const float*)d_in[12], (float*)d_out);
}

// Round 4
// 506.367 us; speedup vs baseline: 1.3739x; 1.3739x over previous
//
#include <hip/hip_runtime.h>

// T=512, B=512, K=8, V=5, H=30, NL=4, NLAB=3
#define TT 512
#define BB 512
#define KK 8
#define HH 30
#define GG 120   // 4*H
#define NLAYER 4

__device__ __forceinline__ float rcp_f(float x) { return __builtin_amdgcn_rcpf(x); }
__device__ __forceinline__ float rdlane_f(float v, int l) {
    return __int_as_float(__builtin_amdgcn_readlane(__float_as_int(v), l));
}
// packed f32 FMA, broadcast operand in SGPR pair (readlane results live in SGPRs)
__device__ __forceinline__ float2 pk_fma_s(float2 a, float2 bs, float2 c) {
    float2 d;
    asm("v_pk_fma_f32 %0, %1, %2, %3" : "=v"(d) : "v"(a), "s"(bs), "v"(c));
    return d;
}
__device__ __forceinline__ float2 pk_add(float2 a, float2 b) {
    float2 d;
    asm("v_pk_add_f32 %0, %1, %2" : "=v"(d) : "v"(a), "v"(b));
    return d;
}
// value from lane^32 partner (valid for lanes < 32; lanes >= 32 get lo value)
__device__ __forceinline__ float swap32_hi(float x) {
    float a = x, b = x;
    asm("v_permlane32_swap_b32 %0, %1" : "+v"(a), "+v"(b));
    return b;   // lanes<32: x[lane+32]
}

// One block = one sample; 4 waves = 4 LSTM layers in the R1-proven ELASTIC
// pipeline (8-deep LDS h-ring + progress counters, no barrier in recurrence).
// R4 lesson (R0 vs R1 vs R3 cross-compare): the ~2184 cyc/step wall is pinned
// by EITHER the VALU issue pipe (R0: readlane-heavy, 70% busy) OR the LDS pipe
// (R1: 30 uniform ds_read/step/wave x 8 waves/CU ~ 66% DS occupancy) — fixing
// one at a time just moves the pin. This version is light on BOTH pipes:
//  - h-side broadcast via v_readlane of the live hprev REGISTER (no LDS
//    round-trip in the recurrence chain, DS ops/step ~2)
//  - x carriers pre-read per 4-step group (compiler can't hoist LDS reads
//    past hring writes itself - alias), x-MACs fill h-chain stalls
//  - 15-deep h accumulator chain split 8+7 with tree join
//  - XOR-32 gate layout: i,g on lanes 0..29; f,o on lanes 32..61; one
//    v_permlane32_swap per exchange (no ds_bpermute)
__global__ __launch_bounds__(256) __attribute__((amdgpu_waves_per_eu(2, 2)))
void rnn_fused(
    const int*   __restrict__ xin,  const float* __restrict__ wxin,
    const float* __restrict__ embed,
    const float* __restrict__ Wih,  const float* __restrict__ Whh,
    const float* __restrict__ bih,  const float* __restrict__ bhh,
    const float* __restrict__ W1,   const float* __restrict__ b1,
    const float* __restrict__ W2,   const float* __restrict__ b2,
    const float* __restrict__ fcW,  const float* __restrict__ fcb,
    float* __restrict__ out)
{
    __shared__ alignas(16) float hstore[TT * HH];        // layer-3 h trace
    __shared__ alignas(16) float seqring[2][16][32];     // pooled-embed (wave-0 private)
    __shared__ alignas(16) int   ringx[4][16][KK];       // x stream (wave-0 private)
    __shared__ alignas(16) float ringw[4][16][KK];
    __shared__ alignas(16) float hring[3][8][32];        // layer->layer h ring
    __shared__ alignas(16) float re_s[5 * HH];           // relu(embed)
    __shared__ alignas(16) float energy_s[TT];
    __shared__ float red_s[16];
    __shared__ float part_s[8][HH];
    __shared__ float pooled_s[HH];
    __shared__ float logits_s[3];
    __shared__ int   sync_s[8];                          // [0..3]=prog, [4..7]=cons

    const int tid  = threadIdx.x;
    const int wv   = tid >> 6;
    const int lane = tid & 63;
    const int b    = blockIdx.x;
    volatile int* vs = sync_s;

    // ---- preamble ----
    if (tid < 8) sync_s[tid] = 0;
    if (tid < 5 * HH) re_s[tid] = fmaxf(embed[tid], 0.0f);

    int4 hx = {0,0,0,0}; float4 hw = {0,0,0,0};          // held x/w (wave0, lanes<32)
    if (wv == 0 && lane < 32) {
        const int r = lane >> 1, hf = lane & 1;
        #pragma unroll
        for (int cc = 0; cc < 2; ++cc) {                 // chunks 0,1 -> LDS
            long off = ((long)(16 * cc + r) * BB + b) * KK + hf * 4;
            *(int4*)(&ringx[cc][r][hf * 4])   = *(const int4*)(xin  + off);
            *(float4*)(&ringw[cc][r][hf * 4]) = *(const float4*)(wxin + off);
        }
        long off2 = ((long)(32 + r) * BB + b) * KK + hf * 4;  // chunk 2 -> regs
        hx = *(const int4*)(xin  + off2);
        hw = *(const float4*)(wxin + off2);
    }

    // ---- per-lane LSTM weights, XOR-32 gate layout ----
    // half0 (lanes 0..31):  rowA = i-row q,    rowB = g-row q+60
    // half1 (lanes 32..63): rowA = f-row q+30, rowB = o-row q+90
    const int half = lane >> 5;
    const int q31  = lane & 31;
    const int qq   = (q31 < HH) ? q31 : (HH - 1);        // clamp dead lanes
    const int rA   = qq + half * HH;                     // 0..59
    const int rB   = rA + 60;                            // 60..119
    float2 wihA[15], wihB[15], whhA[15], whhB[15];
    {
        const float* WihL = Wih + wv * GG * HH;
        const float* WhhL = Whh + wv * GG * HH;
        #pragma unroll
        for (int kk = 0; kk < 15; ++kk) {
            wihA[kk] = *(const float2*)(WihL + rA * HH + 2 * kk);
            wihB[kk] = *(const float2*)(WihL + rB * HH + 2 * kk);
            whhA[kk] = *(const float2*)(WhhL + rA * HH + 2 * kk);
            whhB[kk] = *(const float2*)(WhhL + rB * HH + 2 * kk);
        }
    }
    const float biasA = bih[wv * GG + rA] + bhh[wv * GG + rA];
    const float biasB = bih[wv * GG + rB] + bhh[wv * GG + rB];
    const float mBneg = (lane < 32) ? -2.0f : -1.0f;     // half0: tanh via 2*sig(2x)-1
    const float aB    = (lane < 32) ?  2.0f :  1.0f;
    const float dB    = (lane < 32) ? -1.0f :  0.0f;

    __syncthreads();   // preamble visible (ringx/re_s/sync init)

    float c_val = 0.0f;
    float hprev = 0.0f;

    auto do_step = [&](int t, float xi) {
        // h-side first (chain-critical): broadcast own h via readlane (register)
        float2 ahA = {0.f,0.f}, ahB = {0.f,0.f};
        float2 ahA2 = {0.f,0.f}, ahB2 = {0.f,0.f};
        #pragma unroll
        for (int k = 0; k < 8; ++k) {
            float2 hp;
            hp.x = rdlane_f(hprev, 2 * k);
            hp.y = rdlane_f(hprev, 2 * k + 1);
            ahA = pk_fma_s(whhA[k], hp, ahA);
            ahB = pk_fma_s(whhB[k], hp, ahB);
        }
        #pragma unroll
        for (int k = 8; k < 15; ++k) {
            float2 hp;
            hp.x = rdlane_f(hprev, 2 * k);
            hp.y = rdlane_f(hprev, 2 * k + 1);
            ahA2 = pk_fma_s(whhA[k], hp, ahA2);
            ahB2 = pk_fma_s(whhB[k], hp, ahB2);
        }
        // x-side: independent of h, fills h-chain stalls
        float2 axA = {0.f,0.f}, axB = {0.f,0.f};
        #pragma unroll
        for (int k = 0; k < 15; ++k) {
            float2 xp;
            xp.x = rdlane_f(xi, 2 * k);
            xp.y = rdlane_f(xi, 2 * k + 1);
            axA = pk_fma_s(wihA[k], xp, axA);
            axB = pk_fma_s(wihB[k], xp, axB);
        }
        const float2 s0 = pk_add(pk_add(axA, ahA), ahA2);
        const float2 s1 = pk_add(pk_add(axB, ahB), ahB2);
        const float gA = s0.x + s0.y + biasA;            // i | f
        const float gB = s1.x + s1.y + biasB;            // g | o
        const float actA = rcp_f(1.0f + __expf(-gA));    // sigmoid (both halves)
        const float sB   = rcp_f(1.0f + __expf(gB * mBneg));
        const float actB = fmaf(aB, sB, dB);             // tanh | sigmoid
        const float fI = swap32_hi(actA);                // f from lane+32
        const float oI = swap32_hi(actB);                // o from lane+32
        c_val = fmaf(fI, c_val, actA * actB);            // valid on lanes 0..29
        const float tC = fmaf(2.0f, rcp_f(1.0f + __expf(-2.0f * c_val)), -1.0f);
        const float hv = oI * tC;
        hprev = hv;
        if (lane < HH) {
            if (wv < NLAYER - 1) hring[wv][t & 7][lane] = hv;
            else                 hstore[t * HH + lane]  = hv;
        }
    };

    // ---- elastic pipelined recurrence: 128 groups of 4 steps ----
    for (int T0 = 0; T0 < TT; T0 += 4) {
        if (wv == 0) {
            if ((T0 & 15) == 0) {                        // chunk boundary (private)
                const int c = T0 >> 4;
                if (lane < 32) {
                    const int r = lane >> 1, hf = lane & 1;
                    if (c <= 29) {                       // commit chunk c+2
                        const int sl = (c + 2) & 3;
                        *(int4*)(&ringx[sl][r][hf * 4])   = hx;
                        *(float4*)(&ringw[sl][r][hf * 4]) = hw;
                    }
                    if (c <= 28) {                       // load chunk c+3
                        long off = ((long)(16 * (c + 3) + r) * BB + b) * KK + hf * 4;
                        hx = *(const int4*)(xin  + off);
                        hw = *(const float4*)(wxin + off);
                    }
                }
                const int sl = c & 3, par = c & 1;       // gather pooled chunk c
                #pragma unroll
                for (int rr = 0; rr < 8; ++rr) {
                    const int o = lane + rr * 64;
                    if (o < 480) {
                        const int tr = o / HH, j = o - tr * HH;
                        int4   xa = *(const int4*)(&ringx[sl][tr][0]);
                        int4   xb = *(const int4*)(&ringx[sl][tr][4]);
                        float4 wa = *(const float4*)(&ringw[sl][tr][0]);
                        float4 wb = *(const float4*)(&ringw[sl][tr][4]);
                        float acc = re_s[xa.x * HH + j] * wa.x;
                        acc = fmaf(re_s[xa.y * HH + j], wa.y, acc);
                        acc = fmaf(re_s[xa.z * HH + j], wa.z, acc);
                        acc = fmaf(re_s[xa.w * HH + j], wa.w, acc);
                        acc = fmaf(re_s[xb.x * HH + j], wb.x, acc);
                        acc = fmaf(re_s[xb.y * HH + j], wb.y, acc);
                        acc = fmaf(re_s[xb.z * HH + j], wb.z, acc);
                        acc = fmaf(re_s[xb.w * HH + j], wb.w, acc);
                        seqring[par][tr][j] = acc * 0.125f;
                    }
                }
                __threadfence_block();                   // gather visible to own reads
            }
        } else {
            while (vs[wv - 1] < T0 + 4) __builtin_amdgcn_s_sleep(2);   // x ready
        }
        if (wv < NLAYER - 1) {
            while (vs[4 + wv + 1] < T0 - 4) __builtin_amdgcn_s_sleep(2); // ring free
        }
        __threadfence_block();                           // order spins vs ring reads

        // pre-read the group's 4 x carriers (regs); explicit because the
        // compiler can't hoist these LDS reads past hring writes (alias)
        float xg0, xg1, xg2, xg3;
        if (wv == 0) {
            const float* base = &seqring[(T0 >> 4) & 1][0][0];
            xg0 = base[((T0 + 0) & 15) * 32 + (lane & 31)];
            xg1 = base[((T0 + 1) & 15) * 32 + (lane & 31)];
            xg2 = base[((T0 + 2) & 15) * 32 + (lane & 31)];
            xg3 = base[((T0 + 3) & 15) * 32 + (lane & 31)];
        } else {
            xg0 = hring[wv - 1][(T0 + 0) & 7][lane & 31];
            xg1 = hring[wv - 1][(T0 + 1) & 7][lane & 31];
            xg2 = hring[wv - 1][(T0 + 2) & 7][lane & 31];
            xg3 = hring[wv - 1][(T0 + 3) & 7][lane & 31];
        }
        do_step(T0 + 0, xg0);
        do_step(T0 + 1, xg1);
        do_step(T0 + 2, xg2);
        do_step(T0 + 3, xg3);
        __threadfence_block();                           // drain h writes
        if (lane == 0) {
            if (wv < NLAYER - 1) vs[wv]     = T0 + 4;    // producer progress
            if (wv > 0)          vs[4 + wv] = T0 + 4;    // consumer progress
        }
    }

    __syncthreads();   // hstore complete

    // ---- attention, t-per-lane: e_t = relu(h_t @ W1 + b1) @ W2 + b2 ----
    {
        float w1cx[15], w1cy[15];                        // W1 column `lane`
        #pragma unroll
        for (int k = 0; k < 15; ++k) {
            w1cx[k] = W1[(2 * k) * 64 + lane];
            w1cy[k] = W1[(2 * k + 1) * 64 + lane];
        }
        const float b1v = b1[lane];
        const float w2v = W2[lane];
        const float b2v = b2[0];
        #pragma unroll
        for (int pass = 0; pass < 2; ++pass) {
            const int t = wv * 128 + pass * 64 + lane;   // each lane owns one t
            float2 h2[15];
            #pragma unroll
            for (int k = 0; k < 15; ++k)
                h2[k] = *(const float2*)(hstore + t * HH + 2 * k);
            float e = b2v;
            for (int u = 0; u < 64; ++u) {               // W1 broadcast via readlane
                float2 acc = {0.f, 0.f};
                #pragma unroll
                for (int k = 0; k < 15; ++k) {
                    float2 wp;
                    wp.x = rdlane_f(w1cx[k], u);
                    wp.y = rdlane_f(w1cy[k], u);
                    acc = pk_fma_s(h2[k], wp, acc);
                }
                const float su = acc.x + acc.y + rdlane_f(b1v, u);
                e = fmaf(fmaxf(su, 0.0f), rdlane_f(w2v, u), e);
            }
            energy_s[t] = e;
        }
    }
    __syncthreads();

    // ---- softmax over T ----
    float mx = -3.0e38f;
    for (int i = tid; i < TT; i += 256) mx = fmaxf(mx, energy_s[i]);
    #pragma unroll
    for (int m = 1; m < 64; m <<= 1) mx = fmaxf(mx, __shfl_xor(mx, m, 64));
    if (lane == 0) red_s[wv] = mx;
    __syncthreads();
    mx = fmaxf(fmaxf(red_s[0], red_s[1]), fmaxf(red_s[2], red_s[3]));
    float ssum = 0.0f;
    for (int i = tid; i < TT; i += 256) {
        float ev = __expf(energy_s[i] - mx);
        energy_s[i] = ev;
        ssum += ev;
    }
    #pragma unroll
    for (int m = 1; m < 64; m <<= 1) ssum += __shfl_xor(ssum, m, 64);
    if (lane == 0) red_s[8 + wv] = ssum;
    __syncthreads();
    const float invS = rcp_f(red_s[8] + red_s[9] + red_s[10] + red_s[11]);

    // ---- pooled_j = sum_t softmax_t * h[t][j] ----
    {
        const int g = tid >> 5, jj = tid & 31;
        if (jj < HH) {
            float part = 0.0f;
            for (int t = g; t < TT; t += 8)
                part = fmaf(energy_s[t] * invS, hstore[t * HH + jj], part);
            part_s[g][jj] = part;
        }
    }
    __syncthreads();
    if (tid < HH) {
        float pv = 0.0f;
        #pragma unroll
        for (int q = 0; q < 8; ++q) pv += part_s[q][tid];
        pooled_s[tid] = pv;
    }
    __syncthreads();

    // ---- FC (30->3) + softmax ----
    if (tid < 3) {
        float acc = fcb[tid];
        #pragma unroll
        for (int k = 0; k < HH; ++k) acc = fmaf(pooled_s[k], fcW[k * 3 + tid], acc);
        logits_s[tid] = acc;
    }
    __syncthreads();
    if (tid == 0) {
        float l0 = logits_s[0], l1 = logits_s[1], l2 = logits_s[2];
        float m3 = fmaxf(l0, fmaxf(l1, l2));
        float e0 = __expf(l0 - m3), e1 = __expf(l1 - m3), e2 = __expf(l2 - m3);
        float inv = rcp_f(e0 + e1 + e2);
        out[b * 3 + 0] = e0 * inv; out[b * 3 + 1] = e1 * inv; out[b * 3 + 2] = e2 * inv;
    }
}

extern "C" void kernel_launch(void* const* d_in, const int* in_sizes, int n_in,
                              void* d_out, int out_size, void* d_ws, size_t ws_size,
                              hipStream_t stream)
{
    (void)in_sizes; (void)n_in; (void)d_ws; (void)ws_size; (void)out_size;
    rnn_fused<<<BB, 256, 0, stream>>>(
        (const int*)  d_in[0],  (const float*)d_in[1],  (const float*)d_in[2],
        (const float*)d_in[3],  (const float*)d_in[4],  (const float*)d_in[5],
        (const float*)d_in[6],  (const float*)d_in[7],  (const float*)d_in[8],
        (const float*)d_in[9],  (const float*)d_in[10], (const float*)d_in[11],
        (const float*)d_in[12], (float*)d_out);
}

// Round 6
// 493.042 us; speedup vs baseline: 1.4110x; 1.0270x over previous
//
#include <hip/hip_runtime.h>

// T=512, B=512, K=8, V=5, H=30, NL=4, NLAB=3
#define TT 512
#define BB 512
#define KK 8
#define HH 30
#define GG 120   // 4*H
#define NLAYER 4

__device__ __forceinline__ float rcp_f(float x) { return __builtin_amdgcn_rcpf(x); }
__device__ __forceinline__ float rdlane_f(float v, int l) {
    return __int_as_float(__builtin_amdgcn_readlane(__float_as_int(v), l));
}
// packed f32 FMA, all-VGPR operands (broadcast operand from uniform LDS read)
__device__ __forceinline__ float2 pk_fma_v(float2 a, float2 b, float2 c) {
    float2 d;
    asm("v_pk_fma_f32 %0, %1, %2, %3" : "=v"(d) : "v"(a), "v"(b), "v"(c));
    return d;
}
// packed f32 FMA, broadcast operand in SGPR pair (readlane results live in SGPRs)
__device__ __forceinline__ float2 pk_fma_s(float2 a, float2 bs, float2 c) {
    float2 d;
    asm("v_pk_fma_f32 %0, %1, %2, %3" : "=v"(d) : "v"(a), "s"(bs), "v"(c));
    return d;
}
__device__ __forceinline__ float2 pk_add(float2 a, float2 b) {
    float2 d;
    asm("v_pk_add_f32 %0, %1, %2" : "=v"(d) : "v"(a), "v"(b));
    return d;
}
// value from lane^32 partner (valid for lanes < 32; lanes >= 32 get lo value)
__device__ __forceinline__ float swap32_hi(float x) {
    float a = x, b = x;
    asm("v_permlane32_swap_b32 %0, %1" : "+v"(a), "+v"(b));
    return b;   // lanes<32: x[lane+32]
}

// One block = one sample; 4 waves = 4 LSTM layers in the proven ELASTIC
// pipeline (8-deep LDS h-ring + progress counters, no barrier in recurrence).
// R6: R5's "a"-operand experiment proved VOP3P can't read AGPRs on gfx950, so
// AGPR-parked weights always pay accvgpr_read copies (the R0..R4 phantom VALU
// ops). Fix = stop the parking by shrinking the recurrence's live set:
//  - x-side broadcast via uniform ds_read_b64 (R1 mechanism, free broadcast):
//    -30 readlane/step, -5 carrier regs, x-MACs fill h-chain stalls
//  - h-side broadcast via v_readlane of live hprev register (R4 mechanism):
//    no LDS round-trip in the serial chain
//  - attention W1/b1/W2 pointers LAUNDERED after the loop so their 32
//    loop-invariant loads cannot be hoisted to live across the recurrence
__global__ __launch_bounds__(256) __attribute__((amdgpu_waves_per_eu(2, 2)))
void rnn_fused(
    const int*   __restrict__ xin,  const float* __restrict__ wxin,
    const float* __restrict__ embed,
    const float* __restrict__ Wih,  const float* __restrict__ Whh,
    const float* __restrict__ bih,  const float* __restrict__ bhh,
    const float* __restrict__ W1,   const float* __restrict__ b1,
    const float* __restrict__ W2,   const float* __restrict__ b2,
    const float* __restrict__ fcW,  const float* __restrict__ fcb,
    float* __restrict__ out)
{
    __shared__ alignas(16) float hstore[TT * HH];        // layer-3 h trace
    __shared__ alignas(16) float seqring[2][16][32];     // pooled-embed (wave-0 private)
    __shared__ alignas(16) int   ringx[4][16][KK];       // x stream (wave-0 private)
    __shared__ alignas(16) float ringw[4][16][KK];
    __shared__ alignas(16) float hring[3][8][32];        // layer->layer h ring
    __shared__ alignas(16) float re_s[5 * HH];           // relu(embed)
    __shared__ alignas(16) float energy_s[TT];
    __shared__ float red_s[16];
    __shared__ float part_s[8][HH];
    __shared__ float pooled_s[HH];
    __shared__ float logits_s[3];
    __shared__ int   sync_s[8];                          // [0..3]=prog, [4..7]=cons

    const int tid  = threadIdx.x;
    const int wv   = tid >> 6;
    const int lane = tid & 63;
    const int b    = blockIdx.x;
    volatile int* vs = sync_s;

    // ---- preamble ----
    if (tid < 8) sync_s[tid] = 0;
    if (tid < 5 * HH) re_s[tid] = fmaxf(embed[tid], 0.0f);

    int4 hx = {0,0,0,0}; float4 hw = {0,0,0,0};          // held x/w (wave0, lanes<32)
    if (wv == 0 && lane < 32) {
        const int r = lane >> 1, hf = lane & 1;
        #pragma unroll
        for (int cc = 0; cc < 2; ++cc) {                 // chunks 0,1 -> LDS
            long off = ((long)(16 * cc + r) * BB + b) * KK + hf * 4;
            *(int4*)(&ringx[cc][r][hf * 4])   = *(const int4*)(xin  + off);
            *(float4*)(&ringw[cc][r][hf * 4]) = *(const float4*)(wxin + off);
        }
        long off2 = ((long)(32 + r) * BB + b) * KK + hf * 4;  // chunk 2 -> regs
        hx = *(const int4*)(xin  + off2);
        hw = *(const float4*)(wxin + off2);
    }

    // ---- per-lane LSTM weights, XOR-32 gate layout ----
    // half0 (lanes 0..31):  rowA = i-row q,    rowB = g-row q+60
    // half1 (lanes 32..63): rowA = f-row q+30, rowB = o-row q+90
    const int half = lane >> 5;
    const int q31  = lane & 31;
    const int qq   = (q31 < HH) ? q31 : (HH - 1);        // clamp dead lanes
    const int rA   = qq + half * HH;                     // 0..59
    const int rB   = rA + 60;                            // 60..119
    float2 wihA[15], wihB[15], whhA[15], whhB[15];
    {
        const float* WihL = Wih + wv * GG * HH;
        const float* WhhL = Whh + wv * GG * HH;
        #pragma unroll
        for (int kk = 0; kk < 15; ++kk) {
            wihA[kk] = *(const float2*)(WihL + rA * HH + 2 * kk);
            wihB[kk] = *(const float2*)(WihL + rB * HH + 2 * kk);
            whhA[kk] = *(const float2*)(WhhL + rA * HH + 2 * kk);
            whhB[kk] = *(const float2*)(WhhL + rB * HH + 2 * kk);
        }
    }
    const float biasA = bih[wv * GG + rA] + bhh[wv * GG + rA];
    const float biasB = bih[wv * GG + rB] + bhh[wv * GG + rB];
    const float mBneg = (lane < 32) ? -2.0f : -1.0f;     // half0: tanh via 2*sig(2x)-1
    const float aB    = (lane < 32) ?  2.0f :  1.0f;
    const float dB    = (lane < 32) ? -1.0f :  0.0f;

    __syncthreads();   // preamble visible (ringx/re_s/sync init)

    float c_val = 0.0f;
    float hprev = 0.0f;

    auto do_step = [&](int t) {
        // h-side first (chain-critical): broadcast own h via readlane (register)
        float2 ahA = {0.f,0.f}, ahB = {0.f,0.f};
        float2 ahA2 = {0.f,0.f}, ahB2 = {0.f,0.f};
        #pragma unroll
        for (int k = 0; k < 8; ++k) {
            float2 hp;
            hp.x = rdlane_f(hprev, 2 * k);
            hp.y = rdlane_f(hprev, 2 * k + 1);
            ahA = pk_fma_s(whhA[k], hp, ahA);
            ahB = pk_fma_s(whhB[k], hp, ahB);
        }
        #pragma unroll
        for (int k = 8; k < 15; ++k) {
            float2 hp;
            hp.x = rdlane_f(hprev, 2 * k);
            hp.y = rdlane_f(hprev, 2 * k + 1);
            ahA2 = pk_fma_s(whhA[k], hp, ahA2);
            ahB2 = pk_fma_s(whhB[k], hp, ahB2);
        }
        // x-side: uniform-address LDS reads = free broadcast, off the VALU pipe;
        // independent of h, fills h-chain stalls
        const float* xsrc = (wv == 0) ? &seqring[(t >> 4) & 1][t & 15][0]
                                      : &hring[wv - 1][t & 7][0];
        float2 axA = {0.f,0.f}, axB = {0.f,0.f};
        #pragma unroll
        for (int k = 0; k < 15; ++k) {
            const float2 xp = *(const float2*)(xsrc + 2 * k);
            axA = pk_fma_v(wihA[k], xp, axA);
            axB = pk_fma_v(wihB[k], xp, axB);
        }
        const float2 s0 = pk_add(pk_add(axA, ahA), ahA2);
        const float2 s1 = pk_add(pk_add(axB, ahB), ahB2);
        const float gA = s0.x + s0.y + biasA;            // i | f
        const float gB = s1.x + s1.y + biasB;            // g | o
        const float actA = rcp_f(1.0f + __expf(-gA));    // sigmoid (both halves)
        const float sB   = rcp_f(1.0f + __expf(gB * mBneg));
        const float actB = fmaf(aB, sB, dB);             // tanh | sigmoid
        const float fI = swap32_hi(actA);                // f from lane+32
        const float oI = swap32_hi(actB);                // o from lane+32
        c_val = fmaf(fI, c_val, actA * actB);            // valid on lanes 0..29
        const float tC = fmaf(2.0f, rcp_f(1.0f + __expf(-2.0f * c_val)), -1.0f);
        const float hv = oI * tC;
        hprev = hv;
        if (lane < HH) {
            if (wv < NLAYER - 1) hring[wv][t & 7][lane] = hv;
            else                 hstore[t * HH + lane]  = hv;
        }
    };

    // ---- elastic pipelined recurrence: 128 groups of 4 steps ----
    for (int T0 = 0; T0 < TT; T0 += 4) {
        if (wv == 0) {
            if ((T0 & 15) == 0) {                        // chunk boundary (private)
                const int c = T0 >> 4;
                if (lane < 32) {
                    const int r = lane >> 1, hf = lane & 1;
                    if (c <= 29) {                       // commit chunk c+2
                        const int sl = (c + 2) & 3;
                        *(int4*)(&ringx[sl][r][hf * 4])   = hx;
                        *(float4*)(&ringw[sl][r][hf * 4]) = hw;
                    }
                    if (c <= 28) {                       // load chunk c+3
                        long off = ((long)(16 * (c + 3) + r) * BB + b) * KK + hf * 4;
                        hx = *(const int4*)(xin  + off);
                        hw = *(const float4*)(wxin + off);
                    }
                }
                const int sl = c & 3, par = c & 1;       // gather pooled chunk c
                #pragma unroll
                for (int rr = 0; rr < 8; ++rr) {
                    const int o = lane + rr * 64;
                    if (o < 480) {
                        const int tr = o / HH, j = o - tr * HH;
                        int4   xa = *(const int4*)(&ringx[sl][tr][0]);
                        int4   xb = *(const int4*)(&ringx[sl][tr][4]);
                        float4 wa = *(const float4*)(&ringw[sl][tr][0]);
                        float4 wb = *(const float4*)(&ringw[sl][tr][4]);
                        float acc = re_s[xa.x * HH + j] * wa.x;
                        acc = fmaf(re_s[xa.y * HH + j], wa.y, acc);
                        acc = fmaf(re_s[xa.z * HH + j], wa.z, acc);
                        acc = fmaf(re_s[xa.w * HH + j], wa.w, acc);
                        acc = fmaf(re_s[xb.x * HH + j], wb.x, acc);
                        acc = fmaf(re_s[xb.y * HH + j], wb.y, acc);
                        acc = fmaf(re_s[xb.z * HH + j], wb.z, acc);
                        acc = fmaf(re_s[xb.w * HH + j], wb.w, acc);
                        seqring[par][tr][j] = acc * 0.125f;
                    }
                }
                __threadfence_block();                   // gather visible to own reads
            }
        } else {
            while (vs[wv - 1] < T0 + 4) __builtin_amdgcn_s_sleep(1);   // x ready
        }
        if (wv < NLAYER - 1) {
            while (vs[4 + wv + 1] < T0 - 4) __builtin_amdgcn_s_sleep(1); // ring free
        }
        __threadfence_block();                           // order spins vs ring reads
        do_step(T0 + 0);
        do_step(T0 + 1);
        do_step(T0 + 2);
        do_step(T0 + 3);
        __threadfence_block();                           // drain h writes
        if (lane == 0) {
            if (wv < NLAYER - 1) vs[wv]     = T0 + 4;    // producer progress
            if (wv > 0)          vs[4 + wv] = T0 + 4;    // consumer progress
        }
    }

    __syncthreads();   // hstore complete

    // ---- attention, t-per-lane: e_t = relu(h_t @ W1 + b1) @ W2 + b2 ----
    {
        // launder pointers so these loop-invariant loads CANNOT be hoisted
        // above the recurrence (they'd occupy ~32 VGPRs across the whole loop
        // and trigger AGPR parking of the weight arrays)
        const float* W1p = W1;
        const float* b1p = b1;
        const float* W2p = W2;
        asm volatile("" : "+v"(W1p), "+v"(b1p), "+v"(W2p));

        float w1cx[15], w1cy[15];                        // W1 column `lane`
        #pragma unroll
        for (int k = 0; k < 15; ++k) {
            w1cx[k] = W1p[(2 * k) * 64 + lane];
            w1cy[k] = W1p[(2 * k + 1) * 64 + lane];
        }
        const float b1v = b1p[lane];
        const float w2v = W2p[lane];
        const float b2v = b2[0];
        #pragma unroll
        for (int pass = 0; pass < 2; ++pass) {
            const int t = wv * 128 + pass * 64 + lane;   // each lane owns one t
            float2 h2[15];
            #pragma unroll
            for (int k = 0; k < 15; ++k)
                h2[k] = *(const float2*)(hstore + t * HH + 2 * k);
            float e = b2v;
            for (int u = 0; u < 64; ++u) {               // W1 broadcast via readlane
                float2 acc = {0.f, 0.f};
                #pragma unroll
                for (int k = 0; k < 15; ++k) {
                    float2 wp;
                    wp.x = rdlane_f(w1cx[k], u);
                    wp.y = rdlane_f(w1cy[k], u);
                    acc = pk_fma_s(h2[k], wp, acc);
                }
                const float su = acc.x + acc.y + rdlane_f(b1v, u);
                e = fmaf(fmaxf(su, 0.0f), rdlane_f(w2v, u), e);
            }
            energy_s[t] = e;
        }
    }
    __syncthreads();

    // ---- softmax over T ----
    float mx = -3.0e38f;
    for (int i = tid; i < TT; i += 256) mx = fmaxf(mx, energy_s[i]);
    #pragma unroll
    for (int m = 1; m < 64; m <<= 1) mx = fmaxf(mx, __shfl_xor(mx, m, 64));
    if (lane == 0) red_s[wv] = mx;
    __syncthreads();
    mx = fmaxf(fmaxf(red_s[0], red_s[1]), fmaxf(red_s[2], red_s[3]));
    float ssum = 0.0f;
    for (int i = tid; i < TT; i += 256) {
        float ev = __expf(energy_s[i] - mx);
        energy_s[i] = ev;
        ssum += ev;
    }
    #pragma unroll
    for (int m = 1; m < 64; m <<= 1) ssum += __shfl_xor(ssum, m, 64);
    if (lane == 0) red_s[8 + wv] = ssum;
    __syncthreads();
    const float invS = rcp_f(red_s[8] + red_s[9] + red_s[10] + red_s[11]);

    // ---- pooled_j = sum_t softmax_t * h[t][j] ----
    {
        const int g = tid >> 5, jj = tid & 31;
        if (jj < HH) {
            float part = 0.0f;
            for (int t = g; t < TT; t += 8)
                part = fmaf(energy_s[t] * invS, hstore[t * HH + jj], part);
            part_s[g][jj] = part;
        }
    }
    __syncthreads();
    if (tid < HH) {
        float pv = 0.0f;
        #pragma unroll
        for (int q = 0; q < 8; ++q) pv += part_s[q][tid];
        pooled_s[tid] = pv;
    }
    __syncthreads();

    // ---- FC (30->3) + softmax ----
    if (tid < 3) {
        float acc = fcb[tid];
        #pragma unroll
        for (int k = 0; k < HH; ++k) acc = fmaf(pooled_s[k], fcW[k * 3 + tid], acc);
        logits_s[tid] = acc;
    }
    __syncthreads();
    if (tid == 0) {
        float l0 = logits_s[0], l1 = logits_s[1], l2 = logits_s[2];
        float m3 = fmaxf(l0, fmaxf(l1, l2));
        float e0 = __expf(l0 - m3), e1 = __expf(l1 - m3), e2 = __expf(l2 - m3);
        float inv = rcp_f(e0 + e1 + e2);
        out[b * 3 + 0] = e0 * inv; out[b * 3 + 1] = e1 * inv; out[b * 3 + 2] = e2 * inv;
    }
}

extern "C" void kernel_launch(void* const* d_in, const int* in_sizes, int n_in,
                              void* d_out, int out_size, void* d_ws, size_t ws_size,
                              hipStream_t stream)
{
    (void)in_sizes; (void)n_in; (void)d_ws; (void)ws_size; (void)out_size;
    rnn_fused<<<BB, 256, 0, stream>>>(
        (const int*)  d_in[0],  (const float*)d_in[1],  (const float*)d_in[2],
        (const float*)d_in[3],  (const float*)d_in[4],  (const float*)d_in[5],
        (const float*)d_in[6],  (const float*)d_in[7],  (const float*)d_in[8],
        (const float*)d_in[9],  (const float*)d_in[10], (const float*)d_in[11],
        (const float*)d_in[12], (float*)d_out);
}

// Round 7
// 452.767 us; speedup vs baseline: 1.5366x; 1.0890x over previous
//
#include <hip/hip_runtime.h>

// T=512, B=512, K=8, V=5, H=30, NL=4, NLAB=3
#define TT 512
#define BB 512
#define KK 8
#define HH 30
#define GG 120   // 4*H
#define NLAYER 4

__device__ __forceinline__ float rcp_f(float x) { return __builtin_amdgcn_rcpf(x); }
__device__ __forceinline__ float rdlane_f(float v, int l) {
    return __int_as_float(__builtin_amdgcn_readlane(__float_as_int(v), l));
}
// packed f32 FMA, all-VGPR operands (broadcast operand from uniform LDS read)
__device__ __forceinline__ float2 pk_fma_v(float2 a, float2 b, float2 c) {
    float2 d;
    asm("v_pk_fma_f32 %0, %1, %2, %3" : "=v"(d) : "v"(a), "v"(b), "v"(c));
    return d;
}
// packed f32 FMA, broadcast operand in SGPR pair (readlane results live in SGPRs)
__device__ __forceinline__ float2 pk_fma_s(float2 a, float2 bs, float2 c) {
    float2 d;
    asm("v_pk_fma_f32 %0, %1, %2, %3" : "=v"(d) : "v"(a), "s"(bs), "v"(c));
    return d;
}
__device__ __forceinline__ float2 pk_add(float2 a, float2 b) {
    float2 d;
    asm("v_pk_add_f32 %0, %1, %2" : "=v"(d) : "v"(a), "v"(b));
    return d;
}
// value from lane^32 partner (valid for lanes < 32; lanes >= 32 get lo value)
__device__ __forceinline__ float swap32_hi(float x) {
    float a = x, b = x;
    asm("v_permlane32_swap_b32 %0, %1" : "+v"(a), "+v"(b));
    return b;   // lanes<32: x[lane+32]
}

// One block = one sample; 4 waves = 4 LSTM layers, ELASTIC pipeline.
// R7: the wall (~2170 cyc/step) tracked neither VALU issue (560-1400/SIMD
// across R1/R4/R6) nor DS ops (3-31/step) -> per-wave stall ~1450 cyc/step is
// STRUCTURAL. Two untouched-since-R0 suspects, both fixed here:
//  (a) handoff cadence: groups of 4 -> 8 steps (16-deep hring), halving all
//      per-group sync costs (spins, fences, publish->observe latency);
//  (b) in-step LDS ordering: x-side ds_reads of hring[wv-1] alias the prior
//      step's hring[wv] ds_write for the compiler -> lgkm serialization each
//      step. Preloading all 15 xp float2 at STEP TOP issues the reads early;
//      their latency hides under the 30 register-only h-side MACs.
// Per-sample math is byte-identical to R6 (absmax 0.0).
__global__ __launch_bounds__(256) __attribute__((amdgpu_waves_per_eu(2, 2)))
void rnn_fused(
    const int*   __restrict__ xin,  const float* __restrict__ wxin,
    const float* __restrict__ embed,
    const float* __restrict__ Wih,  const float* __restrict__ Whh,
    const float* __restrict__ bih,  const float* __restrict__ bhh,
    const float* __restrict__ W1,   const float* __restrict__ b1,
    const float* __restrict__ W2,   const float* __restrict__ b2,
    const float* __restrict__ fcW,  const float* __restrict__ fcb,
    float* __restrict__ out)
{
    __shared__ alignas(16) float hstore[TT * HH];        // layer-3 h trace
    __shared__ alignas(16) float seqring[2][16][32];     // pooled-embed (wave-0 private)
    __shared__ alignas(16) int   ringx[4][16][KK];       // x stream (wave-0 private)
    __shared__ alignas(16) float ringw[4][16][KK];
    __shared__ alignas(16) float hring[3][16][32];       // layer->layer h ring (16 deep)
    __shared__ alignas(16) float re_s[5 * HH];           // relu(embed)
    __shared__ alignas(16) float energy_s[TT];
    __shared__ float red_s[16];
    __shared__ float part_s[8][HH];
    __shared__ float pooled_s[HH];
    __shared__ float logits_s[3];
    __shared__ int   sync_s[8];                          // [0..3]=prog, [4..7]=cons

    const int tid  = threadIdx.x;
    const int wv   = tid >> 6;
    const int lane = tid & 63;
    const int b    = blockIdx.x;
    volatile int* vs = sync_s;

    // ---- preamble ----
    if (tid < 8) sync_s[tid] = 0;
    if (tid < 5 * HH) re_s[tid] = fmaxf(embed[tid], 0.0f);

    int4 hx = {0,0,0,0}; float4 hw = {0,0,0,0};          // held x/w (wave0, lanes<32)
    if (wv == 0 && lane < 32) {
        const int r = lane >> 1, hf = lane & 1;
        #pragma unroll
        for (int cc = 0; cc < 2; ++cc) {                 // chunks 0,1 -> LDS
            long off = ((long)(16 * cc + r) * BB + b) * KK + hf * 4;
            *(int4*)(&ringx[cc][r][hf * 4])   = *(const int4*)(xin  + off);
            *(float4*)(&ringw[cc][r][hf * 4]) = *(const float4*)(wxin + off);
        }
        long off2 = ((long)(32 + r) * BB + b) * KK + hf * 4;  // chunk 2 -> regs
        hx = *(const int4*)(xin  + off2);
        hw = *(const float4*)(wxin + off2);
    }

    // ---- per-lane LSTM weights, XOR-32 gate layout ----
    // half0 (lanes 0..31):  rowA = i-row q,    rowB = g-row q+60
    // half1 (lanes 32..63): rowA = f-row q+30, rowB = o-row q+90
    const int half = lane >> 5;
    const int q31  = lane & 31;
    const int qq   = (q31 < HH) ? q31 : (HH - 1);        // clamp dead lanes
    const int rA   = qq + half * HH;                     // 0..59
    const int rB   = rA + 60;                            // 60..119
    float2 wihA[15], wihB[15], whhA[15], whhB[15];
    {
        const float* WihL = Wih + wv * GG * HH;
        const float* WhhL = Whh + wv * GG * HH;
        #pragma unroll
        for (int kk = 0; kk < 15; ++kk) {
            wihA[kk] = *(const float2*)(WihL + rA * HH + 2 * kk);
            wihB[kk] = *(const float2*)(WihL + rB * HH + 2 * kk);
            whhA[kk] = *(const float2*)(WhhL + rA * HH + 2 * kk);
            whhB[kk] = *(const float2*)(WhhL + rB * HH + 2 * kk);
        }
    }
    const float biasA = bih[wv * GG + rA] + bhh[wv * GG + rA];
    const float biasB = bih[wv * GG + rB] + bhh[wv * GG + rB];
    const float mBneg = (lane < 32) ? -2.0f : -1.0f;     // half0: tanh via 2*sig(2x)-1
    const float aB    = (lane < 32) ?  2.0f :  1.0f;
    const float dB    = (lane < 32) ? -1.0f :  0.0f;

    __syncthreads();   // preamble visible (ringx/re_s/sync init)

    float c_val = 0.0f;
    float hprev = 0.0f;

    auto do_step = [&](int t) {
        // x-operand PRELOAD first: the 15 ds_read_b64 issue at step top and
        // their latency hides under the register-only h-side chains below.
        const float* xsrc = (wv == 0) ? &seqring[(t >> 4) & 1][t & 15][0]
                                      : &hring[wv - 1][t & 15][0];
        float2 xp[15];
        #pragma unroll
        for (int k = 0; k < 15; ++k) xp[k] = *(const float2*)(xsrc + 2 * k);

        // h-side (chain-critical): broadcast own h via readlane (register)
        float2 ahA = {0.f,0.f}, ahB = {0.f,0.f};
        float2 ahA2 = {0.f,0.f}, ahB2 = {0.f,0.f};
        #pragma unroll
        for (int k = 0; k < 8; ++k) {
            float2 hp;
            hp.x = rdlane_f(hprev, 2 * k);
            hp.y = rdlane_f(hprev, 2 * k + 1);
            ahA = pk_fma_s(whhA[k], hp, ahA);
            ahB = pk_fma_s(whhB[k], hp, ahB);
        }
        #pragma unroll
        for (int k = 8; k < 15; ++k) {
            float2 hp;
            hp.x = rdlane_f(hprev, 2 * k);
            hp.y = rdlane_f(hprev, 2 * k + 1);
            ahA2 = pk_fma_s(whhA[k], hp, ahA2);
            ahB2 = pk_fma_s(whhB[k], hp, ahB2);
        }
        // x-side MACs from preloaded registers
        float2 axA = {0.f,0.f}, axB = {0.f,0.f};
        #pragma unroll
        for (int k = 0; k < 15; ++k) {
            axA = pk_fma_v(wihA[k], xp[k], axA);
            axB = pk_fma_v(wihB[k], xp[k], axB);
        }
        const float2 s0 = pk_add(pk_add(axA, ahA), ahA2);
        const float2 s1 = pk_add(pk_add(axB, ahB), ahB2);
        const float gA = s0.x + s0.y + biasA;            // i | f
        const float gB = s1.x + s1.y + biasB;            // g | o
        const float actA = rcp_f(1.0f + __expf(-gA));    // sigmoid (both halves)
        const float sB   = rcp_f(1.0f + __expf(gB * mBneg));
        const float actB = fmaf(aB, sB, dB);             // tanh | sigmoid
        const float fI = swap32_hi(actA);                // f from lane+32
        const float oI = swap32_hi(actB);                // o from lane+32
        c_val = fmaf(fI, c_val, actA * actB);            // valid on lanes 0..29
        const float tC = fmaf(2.0f, rcp_f(1.0f + __expf(-2.0f * c_val)), -1.0f);
        const float hv = oI * tC;
        hprev = hv;
        if (lane < HH) {
            if (wv < NLAYER - 1) hring[wv][t & 15][lane] = hv;
            else                 hstore[t * HH + lane]  = hv;
        }
    };

    // ---- elastic pipelined recurrence: 64 groups of 8 steps ----
    for (int T0 = 0; T0 < TT; T0 += 8) {
        if (wv == 0) {
            if ((T0 & 15) == 0) {                        // chunk boundary (private)
                const int c = T0 >> 4;
                if (lane < 32) {
                    const int r = lane >> 1, hf = lane & 1;
                    if (c <= 29) {                       // commit chunk c+2
                        const int sl = (c + 2) & 3;
                        *(int4*)(&ringx[sl][r][hf * 4])   = hx;
                        *(float4*)(&ringw[sl][r][hf * 4]) = hw;
                    }
                    if (c <= 28) {                       // load chunk c+3
                        long off = ((long)(16 * (c + 3) + r) * BB + b) * KK + hf * 4;
                        hx = *(const int4*)(xin  + off);
                        hw = *(const float4*)(wxin + off);
                    }
                }
                const int sl = c & 3, par = c & 1;       // gather pooled chunk c
                #pragma unroll
                for (int rr = 0; rr < 8; ++rr) {
                    const int o = lane + rr * 64;
                    if (o < 480) {
                        const int tr = o / HH, j = o - tr * HH;
                        int4   xa = *(const int4*)(&ringx[sl][tr][0]);
                        int4   xb = *(const int4*)(&ringx[sl][tr][4]);
                        float4 wa = *(const float4*)(&ringw[sl][tr][0]);
                        float4 wb = *(const float4*)(&ringw[sl][tr][4]);
                        float acc = re_s[xa.x * HH + j] * wa.x;
                        acc = fmaf(re_s[xa.y * HH + j], wa.y, acc);
                        acc = fmaf(re_s[xa.z * HH + j], wa.z, acc);
                        acc = fmaf(re_s[xa.w * HH + j], wa.w, acc);
                        acc = fmaf(re_s[xb.x * HH + j], wb.x, acc);
                        acc = fmaf(re_s[xb.y * HH + j], wb.y, acc);
                        acc = fmaf(re_s[xb.z * HH + j], wb.z, acc);
                        acc = fmaf(re_s[xb.w * HH + j], wb.w, acc);
                        seqring[par][tr][j] = acc * 0.125f;
                    }
                }
                __threadfence_block();                   // gather visible to own reads
            }
        } else {
            while (vs[wv - 1] < T0 + 8) __builtin_amdgcn_s_sleep(1);   // x ready
        }
        if (wv < NLAYER - 1) {
            while (vs[4 + wv + 1] < T0 - 8) __builtin_amdgcn_s_sleep(1); // ring free
        }
        __threadfence_block();                           // order spins vs ring reads
        do_step(T0 + 0);
        do_step(T0 + 1);
        do_step(T0 + 2);
        do_step(T0 + 3);
        do_step(T0 + 4);
        do_step(T0 + 5);
        do_step(T0 + 6);
        do_step(T0 + 7);
        __threadfence_block();                           // drain h writes
        if (lane == 0) {
            if (wv < NLAYER - 1) vs[wv]     = T0 + 8;    // producer progress
            if (wv > 0)          vs[4 + wv] = T0 + 8;    // consumer progress
        }
    }

    __syncthreads();   // hstore complete

    // ---- attention, t-per-lane: e_t = relu(h_t @ W1 + b1) @ W2 + b2 ----
    {
        // launder pointers so these loop-invariant loads CANNOT be hoisted
        // above the recurrence (they'd occupy ~32 VGPRs across the whole loop)
        const float* W1p = W1;
        const float* b1p = b1;
        const float* W2p = W2;
        asm volatile("" : "+v"(W1p), "+v"(b1p), "+v"(W2p));

        float w1cx[15], w1cy[15];                        // W1 column `lane`
        #pragma unroll
        for (int k = 0; k < 15; ++k) {
            w1cx[k] = W1p[(2 * k) * 64 + lane];
            w1cy[k] = W1p[(2 * k + 1) * 64 + lane];
        }
        const float b1v = b1p[lane];
        const float w2v = W2p[lane];
        const float b2v = b2[0];
        #pragma unroll
        for (int pass = 0; pass < 2; ++pass) {
            const int t = wv * 128 + pass * 64 + lane;   // each lane owns one t
            float2 h2[15];
            #pragma unroll
            for (int k = 0; k < 15; ++k)
                h2[k] = *(const float2*)(hstore + t * HH + 2 * k);
            float e = b2v;
            for (int u = 0; u < 64; ++u) {               // W1 broadcast via readlane
                float2 acc = {0.f, 0.f};
                #pragma unroll
                for (int k = 0; k < 15; ++k) {
                    float2 wp;
                    wp.x = rdlane_f(w1cx[k], u);
                    wp.y = rdlane_f(w1cy[k], u);
                    acc = pk_fma_s(h2[k], wp, acc);
                }
                const float su = acc.x + acc.y + rdlane_f(b1v, u);
                e = fmaf(fmaxf(su, 0.0f), rdlane_f(w2v, u), e);
            }
            energy_s[t] = e;
        }
    }
    __syncthreads();

    // ---- softmax over T ----
    float mx = -3.0e38f;
    for (int i = tid; i < TT; i += 256) mx = fmaxf(mx, energy_s[i]);
    #pragma unroll
    for (int m = 1; m < 64; m <<= 1) mx = fmaxf(mx, __shfl_xor(mx, m, 64));
    if (lane == 0) red_s[wv] = mx;
    __syncthreads();
    mx = fmaxf(fmaxf(red_s[0], red_s[1]), fmaxf(red_s[2], red_s[3]));
    float ssum = 0.0f;
    for (int i = tid; i < TT; i += 256) {
        float ev = __expf(energy_s[i] - mx);
        energy_s[i] = ev;
        ssum += ev;
    }
    #pragma unroll
    for (int m = 1; m < 64; m <<= 1) ssum += __shfl_xor(ssum, m, 64);
    if (lane == 0) red_s[8 + wv] = ssum;
    __syncthreads();
    const float invS = rcp_f(red_s[8] + red_s[9] + red_s[10] + red_s[11]);

    // ---- pooled_j = sum_t softmax_t * h[t][j] ----
    {
        const int g = tid >> 5, jj = tid & 31;
        if (jj < HH) {
            float part = 0.0f;
            for (int t = g; t < TT; t += 8)
                part = fmaf(energy_s[t] * invS, hstore[t * HH + jj], part);
            part_s[g][jj] = part;
        }
    }
    __syncthreads();
    if (tid < HH) {
        float pv = 0.0f;
        #pragma unroll
        for (int q = 0; q < 8; ++q) pv += part_s[q][tid];
        pooled_s[tid] = pv;
    }
    __syncthreads();

    // ---- FC (30->3) + softmax ----
    if (tid < 3) {
        float acc = fcb[tid];
        #pragma unroll
        for (int k = 0; k < HH; ++k) acc = fmaf(pooled_s[k], fcW[k * 3 + tid], acc);
        logits_s[tid] = acc;
    }
    __syncthreads();
    if (tid == 0) {
        float l0 = logits_s[0], l1 = logits_s[1], l2 = logits_s[2];
        float m3 = fmaxf(l0, fmaxf(l1, l2));
        float e0 = __expf(l0 - m3), e1 = __expf(l1 - m3), e2 = __expf(l2 - m3);
        float inv = rcp_f(e0 + e1 + e2);
        out[b * 3 + 0] = e0 * inv; out[b * 3 + 1] = e1 * inv; out[b * 3 + 2] = e2 * inv;
    }
}

extern "C" void kernel_launch(void* const* d_in, const int* in_sizes, int n_in,
                              void* d_out, int out_size, void* d_ws, size_t ws_size,
                              hipStream_t stream)
{
    (void)in_sizes; (void)n_in; (void)d_ws; (void)ws_size; (void)out_size;
    rnn_fused<<<BB, 256, 0, stream>>>(
        (const int*)  d_in[0],  (const float*)d_in[1],  (const float*)d_in[2],
        (const float*)d_in[3],  (const float*)d_in[4],  (const float*)d_in[5],
        (const float*)d_in[6],  (const float*)d_in[7],  (const float*)d_in[8],
        (const float*)d_in[9],  (const float*)d_in[10], (const float*)d_in[11],
        (const float*)d_in[12], (float*)d_out);
}

// Round 8
// 443.685 us; speedup vs baseline: 1.5680x; 1.0205x over previous
//
#include <hip/hip_runtime.h>

// T=512, B=512, K=8, V=5, H=30, NL=4, NLAB=3
#define TT 512
#define BB 512
#define KK 8
#define HH 30
#define GG 120   // 4*H
#define NLAYER 4

typedef _Float16 half2v __attribute__((ext_vector_type(2)));

__device__ __forceinline__ float rcp_f(float x) { return __builtin_amdgcn_rcpf(x); }
__device__ __forceinline__ float rdlane_f(float v, int l) {
    return __int_as_float(__builtin_amdgcn_readlane(__float_as_int(v), l));
}
__device__ __forceinline__ unsigned int rdlane_u(unsigned int v, int l) {
    return (unsigned int)__builtin_amdgcn_readlane((int)v, l);
}
__device__ __forceinline__ half2v as_h2(unsigned int u) {
    union { unsigned int u; half2v h; } c; c.u = u; return c.h;
}
// packed f32 FMA, broadcast operand in SGPR pair (attention epilogue)
__device__ __forceinline__ float2 pk_fma_s(float2 a, float2 bs, float2 c) {
    float2 d;
    asm("v_pk_fma_f32 %0, %1, %2, %3" : "=v"(d) : "v"(a), "s"(bs), "v"(c));
    return d;
}
// value from lane^32 partner (valid for lanes < 32; lanes >= 32 get lo value)
__device__ __forceinline__ float swap32_hi(float x) {
    float a = x, b = x;
    asm("v_permlane32_swap_b32 %0, %1" : "+v"(a), "+v"(b));
    return b;   // lanes<32: x[lane+32]
}

// One block = one sample; 4 waves = 4 LSTM layers, R7-proven ELASTIC pipeline
// (16-deep LDS h-ring + progress counters, 8-step groups, no barrier in loop).
// R8: issue model finally closed (pk_fma_f32 = 4 cyc wave64; readlane->SGPR
// hazard ~6 cyc): per-wave ~650-700 issue-cyc/step x 2 waves = 66% busy ==
// measured. TLP capped at 2 blocks/CU (grid 512). So: halve per-wave issue:
//  - v_dot2_f32_f16 MACs (2 dims/instr, full rate, F32 ACCUMULATE): weight
//    regs 120->60 (ends AGPR parking), MAC issue 240->120 cyc
//  - h packed into f16 pairs (cvt + DPP quad-perm + or): 15 readlanes/step
//    instead of 30; x read from ring as packed pairs (4 uniform ds_read_b128)
//  - 8-step loop NOT unrolled (body ~1KB: kills any I$-streaming stall)
// hstore stays f32 -> attention epilogue numerically unchanged.
__global__ __launch_bounds__(256) __attribute__((amdgpu_waves_per_eu(2, 2)))
void rnn_fused(
    const int*   __restrict__ xin,  const float* __restrict__ wxin,
    const float* __restrict__ embed,
    const float* __restrict__ Wih,  const float* __restrict__ Whh,
    const float* __restrict__ bih,  const float* __restrict__ bhh,
    const float* __restrict__ W1,   const float* __restrict__ b1,
    const float* __restrict__ W2,   const float* __restrict__ b2,
    const float* __restrict__ fcW,  const float* __restrict__ fcb,
    float* __restrict__ out)
{
    __shared__ alignas(16) float hstore[TT * HH];              // layer-3 h trace (f32)
    __shared__ alignas(16) unsigned int seqring16[2][16][16];  // pooled-embed, f16 pairs
    __shared__ alignas(16) int   ringx[4][16][KK];             // x stream (wave-0 private)
    __shared__ alignas(16) float ringw[4][16][KK];
    __shared__ alignas(16) unsigned int hring16[3][16][16];    // layer->layer h, f16 pairs
    __shared__ alignas(16) float re_s[5 * HH];                 // relu(embed)
    __shared__ alignas(16) float energy_s[TT];
    __shared__ float red_s[16];
    __shared__ float part_s[8][HH];
    __shared__ float pooled_s[HH];
    __shared__ float logits_s[3];
    __shared__ int   sync_s[8];                                // [0..3]=prog, [4..7]=cons

    const int tid  = threadIdx.x;
    const int wv   = tid >> 6;
    const int lane = tid & 63;
    const int b    = blockIdx.x;
    volatile int* vs = sync_s;

    // ---- preamble ----
    if (tid < 8) sync_s[tid] = 0;
    if (tid < 5 * HH) re_s[tid] = fmaxf(embed[tid], 0.0f);

    int4 hx = {0,0,0,0}; float4 hw = {0,0,0,0};          // held x/w (wave0, lanes<32)
    if (wv == 0 && lane < 32) {
        const int r = lane >> 1, hf = lane & 1;
        #pragma unroll
        for (int cc = 0; cc < 2; ++cc) {                 // chunks 0,1 -> LDS
            long off = ((long)(16 * cc + r) * BB + b) * KK + hf * 4;
            *(int4*)(&ringx[cc][r][hf * 4])   = *(const int4*)(xin  + off);
            *(float4*)(&ringw[cc][r][hf * 4]) = *(const float4*)(wxin + off);
        }
        long off2 = ((long)(32 + r) * BB + b) * KK + hf * 4;  // chunk 2 -> regs
        hx = *(const int4*)(xin  + off2);
        hw = *(const float4*)(wxin + off2);
    }

    // ---- per-lane LSTM weights, XOR-32 gate layout, packed f16 pairs ----
    // half0 (lanes 0..31):  rowA = i-row q,    rowB = g-row q+60
    // half1 (lanes 32..63): rowA = f-row q+30, rowB = o-row q+90
    const int half = lane >> 5;
    const int q31  = lane & 31;
    const int qq   = (q31 < HH) ? q31 : (HH - 1);        // clamp dead lanes
    const int rA   = qq + half * HH;                     // 0..59
    const int rB   = rA + 60;                            // 60..119
    half2v wihA_h[15], wihB_h[15], whhA_h[15], whhB_h[15];
    {
        const float* WihL = Wih + wv * GG * HH;
        const float* WhhL = Whh + wv * GG * HH;
        #pragma unroll
        for (int kk = 0; kk < 15; ++kk) {
            float2 a0 = *(const float2*)(WihL + rA * HH + 2 * kk);
            float2 a1 = *(const float2*)(WihL + rB * HH + 2 * kk);
            float2 a2 = *(const float2*)(WhhL + rA * HH + 2 * kk);
            float2 a3 = *(const float2*)(WhhL + rB * HH + 2 * kk);
            wihA_h[kk][0] = (_Float16)a0.x; wihA_h[kk][1] = (_Float16)a0.y;
            wihB_h[kk][0] = (_Float16)a1.x; wihB_h[kk][1] = (_Float16)a1.y;
            whhA_h[kk][0] = (_Float16)a2.x; whhA_h[kk][1] = (_Float16)a2.y;
            whhB_h[kk][0] = (_Float16)a3.x; whhB_h[kk][1] = (_Float16)a3.y;
        }
    }
    const float biasA = bih[wv * GG + rA] + bhh[wv * GG + rA];
    const float biasB = bih[wv * GG + rB] + bhh[wv * GG + rB];
    const float mBneg = (lane < 32) ? -2.0f : -1.0f;     // half0: tanh via 2*sig(2x)-1
    const float aB    = (lane < 32) ?  2.0f :  1.0f;
    const float dB    = (lane < 32) ? -1.0f :  0.0f;

    __syncthreads();   // preamble visible (ringx/re_s/sync init)

    float c_val = 0.0f;
    unsigned int hpk = 0;   // own h as packed f16 pair: even lane 2k holds (h2k, h2k+1)

    auto do_step = [&](int t) {
        // x operand: packed f16 pairs from ring, uniform-address b128 reads
        const unsigned int* xsrc = (wv == 0) ? &seqring16[(t >> 4) & 1][t & 15][0]
                                             : &hring16[wv - 1][t & 15][0];
        uint4 q0 = ((const uint4*)xsrc)[0];
        uint4 q1 = ((const uint4*)xsrc)[1];
        uint4 q2 = ((const uint4*)xsrc)[2];
        uint4 q3 = ((const uint4*)xsrc)[3];
        const unsigned int xu[16] = {q0.x,q0.y,q0.z,q0.w, q1.x,q1.y,q1.z,q1.w,
                                     q2.x,q2.y,q2.z,q2.w, q3.x,q3.y,q3.z,q3.w};
        // h-side (chain-critical): 15 readlanes of packed pairs (even lanes)
        float ahA = 0.f, ahB = 0.f, ahA2 = 0.f, ahB2 = 0.f;
        #pragma unroll
        for (int k = 0; k < 8; ++k) {
            const half2v hp = as_h2(rdlane_u(hpk, 2 * k));
            ahA = __builtin_amdgcn_fdot2(whhA_h[k], hp, ahA, false);
            ahB = __builtin_amdgcn_fdot2(whhB_h[k], hp, ahB, false);
        }
        #pragma unroll
        for (int k = 8; k < 15; ++k) {
            const half2v hp = as_h2(rdlane_u(hpk, 2 * k));
            ahA2 = __builtin_amdgcn_fdot2(whhA_h[k], hp, ahA2, false);
            ahB2 = __builtin_amdgcn_fdot2(whhB_h[k], hp, ahB2, false);
        }
        // x-side: independent of h, fills h-chain stalls
        float axA = 0.f, axB = 0.f;
        #pragma unroll
        for (int k = 0; k < 15; ++k) {
            const half2v xp = as_h2(xu[k]);
            axA = __builtin_amdgcn_fdot2(wihA_h[k], xp, axA, false);
            axB = __builtin_amdgcn_fdot2(wihB_h[k], xp, axB, false);
        }
        const float gA = (axA + ahA) + (ahA2 + biasA);   // i | f
        const float gB = (axB + ahB) + (ahB2 + biasB);   // g | o
        const float actA = rcp_f(1.0f + __expf(-gA));    // sigmoid (both halves)
        const float sB   = rcp_f(1.0f + __expf(gB * mBneg));
        const float actB = fmaf(aB, sB, dB);             // tanh | sigmoid
        const float fI = swap32_hi(actA);                // f from lane+32
        const float oI = swap32_hi(actB);                // o from lane+32
        c_val = fmaf(fI, c_val, actA * actB);            // valid on lanes 0..29
        const float tC = fmaf(2.0f, rcp_f(1.0f + __expf(-2.0f * c_val)), -1.0f);
        const float hv = oI * tC;
        // pack f16 pair: own (lo) | quad-perm partner (hi) -- valid on even lanes
        union { _Float16 f[2]; unsigned int u; } cv; cv.u = 0;
        cv.f[0] = (_Float16)hv;
        const unsigned int hu  = cv.u;
        const unsigned int hup = (unsigned int)__builtin_amdgcn_mov_dpp(
                                     (int)hu, 0xB1, 0xF, 0xF, true); // quad_perm [1,0,3,2]
        hpk = hu | (hup << 16);
        if (lane < HH) {
            if (wv == NLAYER - 1) hstore[t * HH + lane] = hv;          // f32 trace
            else if (!(lane & 1)) hring16[wv][t & 15][lane >> 1] = hpk; // f16 pairs
        }
    };

    // ---- elastic pipelined recurrence: 64 groups of 8 steps ----
    for (int T0 = 0; T0 < TT; T0 += 8) {
        if (wv == 0) {
            if ((T0 & 15) == 0) {                        // chunk boundary (private)
                const int c = T0 >> 4;
                if (lane < 32) {
                    const int r = lane >> 1, hf = lane & 1;
                    if (c <= 29) {                       // commit chunk c+2
                        const int sl = (c + 2) & 3;
                        *(int4*)(&ringx[sl][r][hf * 4])   = hx;
                        *(float4*)(&ringw[sl][r][hf * 4]) = hw;
                    }
                    if (c <= 28) {                       // load chunk c+3
                        long off = ((long)(16 * (c + 3) + r) * BB + b) * KK + hf * 4;
                        hx = *(const int4*)(xin  + off);
                        hw = *(const float4*)(wxin + off);
                    }
                }
                const int sl = c & 3, par = c & 1;       // gather pooled chunk c
                #pragma unroll
                for (int rr = 0; rr < 8; ++rr) {
                    const int o = lane + rr * 64;
                    if (o < 480) {
                        const int tr = o / HH, j = o - tr * HH;
                        int4   xa = *(const int4*)(&ringx[sl][tr][0]);
                        int4   xb = *(const int4*)(&ringx[sl][tr][4]);
                        float4 wa = *(const float4*)(&ringw[sl][tr][0]);
                        float4 wb = *(const float4*)(&ringw[sl][tr][4]);
                        float acc = re_s[xa.x * HH + j] * wa.x;
                        acc = fmaf(re_s[xa.y * HH + j], wa.y, acc);
                        acc = fmaf(re_s[xa.z * HH + j], wa.z, acc);
                        acc = fmaf(re_s[xa.w * HH + j], wa.w, acc);
                        acc = fmaf(re_s[xb.x * HH + j], wb.x, acc);
                        acc = fmaf(re_s[xb.y * HH + j], wb.y, acc);
                        acc = fmaf(re_s[xb.z * HH + j], wb.z, acc);
                        acc = fmaf(re_s[xb.w * HH + j], wb.w, acc);
                        // store pooled value as f16 (u16 element j of the pair row)
                        ((_Float16*)&seqring16[par][tr][0])[j] = (_Float16)(acc * 0.125f);
                    }
                }
                __threadfence_block();                   // gather visible to own reads
            }
        } else {
            while (vs[wv - 1] < T0 + 8) __builtin_amdgcn_s_sleep(1);   // x ready
        }
        if (wv < NLAYER - 1) {
            while (vs[4 + wv + 1] < T0 - 8) __builtin_amdgcn_s_sleep(1); // ring free
        }
        __threadfence_block();                           // order spins vs ring reads
        #pragma unroll 1
        for (int tt = 0; tt < 8; ++tt)                   // NOT unrolled: ~1KB body
            do_step(T0 + tt);
        __threadfence_block();                           // drain h writes
        if (lane == 0) {
            if (wv < NLAYER - 1) vs[wv]     = T0 + 8;    // producer progress
            if (wv > 0)          vs[4 + wv] = T0 + 8;    // consumer progress
        }
    }

    __syncthreads();   // hstore complete

    // ---- attention, t-per-lane: e_t = relu(h_t @ W1 + b1) @ W2 + b2 ----
    {
        // launder pointers so these loop-invariant loads CANNOT be hoisted
        // above the recurrence
        const float* W1p = W1;
        const float* b1p = b1;
        const float* W2p = W2;
        asm volatile("" : "+v"(W1p), "+v"(b1p), "+v"(W2p));

        float w1cx[15], w1cy[15];                        // W1 column `lane`
        #pragma unroll
        for (int k = 0; k < 15; ++k) {
            w1cx[k] = W1p[(2 * k) * 64 + lane];
            w1cy[k] = W1p[(2 * k + 1) * 64 + lane];
        }
        const float b1v = b1p[lane];
        const float w2v = W2p[lane];
        const float b2v = b2[0];
        #pragma unroll
        for (int pass = 0; pass < 2; ++pass) {
            const int t = wv * 128 + pass * 64 + lane;   // each lane owns one t
            float2 h2[15];
            #pragma unroll
            for (int k = 0; k < 15; ++k)
                h2[k] = *(const float2*)(hstore + t * HH + 2 * k);
            float e = b2v;
            for (int u = 0; u < 64; ++u) {               // W1 broadcast via readlane
                float2 acc = {0.f, 0.f};
                #pragma unroll
                for (int k = 0; k < 15; ++k) {
                    float2 wp;
                    wp.x = rdlane_f(w1cx[k], u);
                    wp.y = rdlane_f(w1cy[k], u);
                    acc = pk_fma_s(h2[k], wp, acc);
                }
                const float su = acc.x + acc.y + rdlane_f(b1v, u);
                e = fmaf(fmaxf(su, 0.0f), rdlane_f(w2v, u), e);
            }
            energy_s[t] = e;
        }
    }
    __syncthreads();

    // ---- softmax over T ----
    float mx = -3.0e38f;
    for (int i = tid; i < TT; i += 256) mx = fmaxf(mx, energy_s[i]);
    #pragma unroll
    for (int m = 1; m < 64; m <<= 1) mx = fmaxf(mx, __shfl_xor(mx, m, 64));
    if (lane == 0) red_s[wv] = mx;
    __syncthreads();
    mx = fmaxf(fmaxf(red_s[0], red_s[1]), fmaxf(red_s[2], red_s[3]));
    float ssum = 0.0f;
    for (int i = tid; i < TT; i += 256) {
        float ev = __expf(energy_s[i] - mx);
        energy_s[i] = ev;
        ssum += ev;
    }
    #pragma unroll
    for (int m = 1; m < 64; m <<= 1) ssum += __shfl_xor(ssum, m, 64);
    if (lane == 0) red_s[8 + wv] = ssum;
    __syncthreads();
    const float invS = rcp_f(red_s[8] + red_s[9] + red_s[10] + red_s[11]);

    // ---- pooled_j = sum_t softmax_t * h[t][j] ----
    {
        const int g = tid >> 5, jj = tid & 31;
        if (jj < HH) {
            float part = 0.0f;
            for (int t = g; t < TT; t += 8)
                part = fmaf(energy_s[t] * invS, hstore[t * HH + jj], part);
            part_s[g][jj] = part;
        }
    }
    __syncthreads();
    if (tid < HH) {
        float pv = 0.0f;
        #pragma unroll
        for (int q = 0; q < 8; ++q) pv += part_s[q][tid];
        pooled_s[tid] = pv;
    }
    __syncthreads();

    // ---- FC (30->3) + softmax ----
    if (tid < 3) {
        float acc = fcb[tid];
        #pragma unroll
        for (int k = 0; k < HH; ++k) acc = fmaf(pooled_s[k], fcW[k * 3 + tid], acc);
        logits_s[tid] = acc;
    }
    __syncthreads();
    if (tid == 0) {
        float l0 = logits_s[0], l1 = logits_s[1], l2 = logits_s[2];
        float m3 = fmaxf(l0, fmaxf(l1, l2));
        float e0 = __expf(l0 - m3), e1 = __expf(l1 - m3), e2 = __expf(l2 - m3);
        float inv = rcp_f(e0 + e1 + e2);
        out[b * 3 + 0] = e0 * inv; out[b * 3 + 1] = e1 * inv; out[b * 3 + 2] = e2 * inv;
    }
}

extern "C" void kernel_launch(void* const* d_in, const int* in_sizes, int n_in,
                              void* d_out, int out_size, void* d_ws, size_t ws_size,
                              hipStream_t stream)
{
    (void)in_sizes; (void)n_in; (void)d_ws; (void)ws_size; (void)out_size;
    rnn_fused<<<BB, 256, 0, stream>>>(
        (const int*)  d_in[0],  (const float*)d_in[1],  (const float*)d_in[2],
        (const float*)d_in[3],  (const float*)d_in[4],  (const float*)d_in[5],
        (const float*)d_in[6],  (const float*)d_in[7],  (const float*)d_in[8],
        (const float*)d_in[9],  (const float*)d_in[10], (const float*)d_in[11],
        (const float*)d_in[12], (float*)d_out);
}